// Round 6
// baseline (2354.010 us; speedup 1.0000x reference)
//
#include <hip/hip_runtime.h>
#include <hip/hip_bf16.h>

#define NL 6
#define DT 6144
#define DM 768
#define TOK 128

#define TD 256            // decode d-tile width
#define NTD 3             // d-tiles
#define FC 384            // decode f-chunk
#define NFC 16            // f-chunks
#define NSTEP (FC / 32)   // 12 k-steps per decode block

// MEASUREMENT ROUND: rep counts to force all kernels into rocprof top-5
#define IREP 128
#define EREP 24
#define DREP 8

using bf16x8 = __attribute__((ext_vector_type(8))) short;
using f32x4  = __attribute__((ext_vector_type(4))) float;

typedef unsigned int u32;
typedef __attribute__((address_space(1))) const u32 gu32;
typedef __attribute__((address_space(3))) u32 lu32;

// async global->LDS, 16B per lane; LDS dest = wave-uniform base + lane*16
__device__ __forceinline__ void stage16(const float* g, float* l) {
  __builtin_amdgcn_global_load_lds((gu32*)g, (lu32*)l, 16, 0, 0);
}

// round-to-nearest-even f32 -> bf16 (branchless; inputs are finite)
__device__ __forceinline__ short f2bf(float f) {
  union { float f; unsigned u; } c; c.f = f;
  unsigned u = c.u;
  u += 0x7fffu + ((u >> 16) & 1u);
  return (short)(u >> 16);
}

// out[j][n][d] = b_dec[j][d]  AND  xb = bf16(x)
__global__ void initcvt_k(const float* __restrict__ b_dec,
                          const float* __restrict__ x,
                          float* __restrict__ out, ushort* __restrict__ xb) {
  #pragma unroll 1
  for (int rep = 0; rep < IREP; ++rep) {
    int idx = blockIdx.x * 256 + threadIdx.x;
    if (idx < NL * TOK * DM) {
      out[idx] = b_dec[(idx / (TOK * DM)) * DM + (idx % DM)];
      xb[idx] = (ushort)f2bf(x[idx]);
    }
  }
}

// acts[l][n][f] = relu(x[l] @ W_enc[l]^T + b_enc[l]), bf16 output.
// Structure byte-identical to round 5; body repeated EREP times (idempotent).
__global__ __launch_bounds__(256) void encode_k(
    const ushort* __restrict__ xb, const float* __restrict__ W_enc,
    const float* __restrict__ b_enc, ushort* __restrict__ acts)
{
  __shared__ float lw[2][64][32];   // 16 KB double-buffered W tile

  const int l  = blockIdx.x / 96;
  const int f0 = (blockIdx.x % 96) * 64;
  const int w    = threadIdx.x >> 6;
  const int lane = threadIdx.x & 63;
  const int lo = lane & 15, hi = lane >> 4;

  const float*  We = W_enc + ((size_t)l * DT + f0) * DM;
  const ushort* Xb = xb + (size_t)l * TOK * DM;

  const int r0 = w * 16 + (lane >> 3);   // staging row (+q*8)
  const int cc = (lane & 7) * 4;         // d-chunk offset (floats)

  #pragma unroll 1
  for (int rep = 0; rep < EREP; ++rep) {
    f32x4 acc[8];
    #pragma unroll
    for (int mi = 0; mi < 8; ++mi) acc[mi] = f32x4{0.f, 0.f, 0.f, 0.f};

    #pragma unroll
    for (int q = 0; q < 2; ++q)
      stage16(We + (size_t)(r0 + q * 8) * DM + cc, &lw[0][w * 16 + q * 8][0]);
    __syncthreads();

    int cur = 0;
    #pragma unroll 1
    for (int s = 0; s < DM / 32; ++s) {
      if (s + 1 < DM / 32) {
        #pragma unroll
        for (int q = 0; q < 2; ++q)
          stage16(We + (size_t)(r0 + q * 8) * DM + (s + 1) * 32 + cc,
                  &lw[cur ^ 1][w * 16 + q * 8][0]);
      }

      bf16x8 b;
      #pragma unroll
      for (int e = 0; e < 8; ++e)
        b[e] = f2bf(lw[cur][w * 16 + lo][hi * 8 + e]);

      bf16x8 a[8];
      #pragma unroll
      for (int mi = 0; mi < 8; ++mi)
        a[mi] = *(const bf16x8*)(Xb + (size_t)(mi * 16 + lo) * DM + s * 32 + hi * 8);

      #pragma unroll
      for (int mi = 0; mi < 8; ++mi)
        acc[mi] = __builtin_amdgcn_mfma_f32_16x16x32_bf16(a[mi], b, acc[mi], 0, 0, 0);

      __syncthreads();
      cur ^= 1;
    }

    const int f = f0 + w * 16 + lo;
    const float bias = b_enc[l * DT + f];
    #pragma unroll
    for (int mi = 0; mi < 8; ++mi) {
      #pragma unroll
      for (int rr = 0; rr < 4; ++rr) {
        const int n = mi * 16 + hi * 4 + rr;
        float v = acc[mi][rr] + bias;
        v = v > 0.f ? v : 0.f;
        acts[((size_t)l * TOK + n) * DT + f] = (ushort)f2bf(v);
      }
    }
    __syncthreads();
  }
}

// pair enumeration (i <= j), 21 valid decoder blocks
__device__ const int PI_[21] = {0,0,0,0,0,0, 1,1,1,1,1, 2,2,2,2, 3,3,3, 4,4, 5};
__device__ const int PJ_[21] = {0,1,2,3,4,5, 1,2,3,4,5, 2,3,4,5, 3,4,5, 4,5, 5};

// out[j] += acts[i] @ W_dec[i][j]; structure byte-identical to round 5;
// k-sweep repeated DREP times into same acc, scaled 1/DREP (exact).
__global__ __launch_bounds__(256, 2) void decode_k(
    const ushort* __restrict__ acts, const float* __restrict__ W_dec,
    float* __restrict__ out)
{
  __shared__ float lw[2][32][TD];   // 64 KB

  const int bid = blockIdx.x;
  const int p  = bid / (NTD * NFC);
  const int rm = bid % (NTD * NFC);
  const int c  = rm / NTD;
  const int t  = rm % NTD;
  const int i = PI_[p], j = PJ_[p];
  const int w = threadIdx.x >> 6;
  const int lane = threadIdx.x & 63;
  const int lo = lane & 15, hi = lane >> 4;
  const int fb = c * FC;

  const float*  Wb = W_dec + ((size_t)(i * NL + j) * DT + fb) * DM + t * TD;
  const ushort* Ab = acts + (size_t)i * TOK * DT + fb;

  f32x4 acc[8][4];
  #pragma unroll
  for (int mi = 0; mi < 8; ++mi)
    #pragma unroll
    for (int ni = 0; ni < 4; ++ni)
      acc[mi][ni] = f32x4{0.f, 0.f, 0.f, 0.f};

  #pragma unroll 1
  for (int rep = 0; rep < DREP; ++rep) {
    #pragma unroll
    for (int q = 0; q < 8; ++q) {
      const int row = w * 8 + q;
      stage16(Wb + (size_t)row * DM + lane * 4, &lw[0][row][0]);
    }
    __syncthreads();

    int cur = 0;
    #pragma unroll 1
    for (int s = 0; s < NSTEP; ++s) {
      if (s + 1 < NSTEP) {
        const float* Ws = Wb + (size_t)(s + 1) * 32 * DM;
        #pragma unroll
        for (int q = 0; q < 8; ++q) {
          const int row = w * 8 + q;
          stage16(Ws + (size_t)row * DM + lane * 4, &lw[cur ^ 1][row][0]);
        }
      }

      bf16x8 a[8];
      #pragma unroll
      for (int mi = 0; mi < 8; ++mi)
        a[mi] = *(const bf16x8*)(Ab + (size_t)(mi * 16 + lo) * DT + s * 32 + hi * 8);

      bf16x8 b[4];
      #pragma unroll
      for (int ni = 0; ni < 4; ++ni) {
        const int col = w * 64 + ni * 16 + lo;
        #pragma unroll
        for (int e = 0; e < 8; ++e)
          b[ni][e] = f2bf(lw[cur][hi * 8 + e][col]);
      }

      #pragma unroll
      for (int mi = 0; mi < 8; ++mi)
        #pragma unroll
        for (int ni = 0; ni < 4; ++ni)
          acc[mi][ni] = __builtin_amdgcn_mfma_f32_16x16x32_bf16(a[mi], b[ni], acc[mi][ni], 0, 0, 0);

      __syncthreads();
      cur ^= 1;
    }
  }

  const float scale = 1.0f / DREP;   // exact (pow2)
  float* oj = out + (size_t)j * TOK * DM;
  #pragma unroll
  for (int ni = 0; ni < 4; ++ni) {
    const int d = t * TD + w * 64 + ni * 16 + lo;
    #pragma unroll
    for (int mi = 0; mi < 8; ++mi)
      #pragma unroll
      for (int rr = 0; rr < 4; ++rr)
        atomicAdd(oj + (size_t)(mi * 16 + hi * 4 + rr) * DM + d, acc[mi][ni][rr] * scale);
  }
}

extern "C" void kernel_launch(void* const* d_in, const int* in_sizes, int n_in,
                              void* d_out, int out_size, void* d_ws, size_t ws_size,
                              hipStream_t stream) {
  const float* x     = (const float*)d_in[0];
  const float* W_enc = (const float*)d_in[1];
  const float* b_enc = (const float*)d_in[2];
  const float* b_dec = (const float*)d_in[3];
  const float* W_dec = (const float*)d_in[4];
  float* out = (float*)d_out;
  ushort* acts = (ushort*)d_ws;                      // 6*128*6144 bf16 = 9.44 MB
  ushort* xb   = acts + (size_t)NL * TOK * DT;       // 6*128*768 bf16 = 1.18 MB

  initcvt_k<<<dim3((NL * TOK * DM + 255) / 256), dim3(256), 0, stream>>>(b_dec, x, out, xb);
  encode_k<<<dim3(NL * 96), dim3(256), 0, stream>>>(xb, W_enc, b_enc, acts);
  decode_k<<<dim3(21 * NFC * NTD), dim3(256), 0, stream>>>(acts, W_dec, out);
}

// Round 7
// 254.232 us; speedup vs baseline: 9.2593x; 9.2593x over previous
//
#include <hip/hip_runtime.h>
#include <hip/hip_bf16.h>

#define NL 6
#define DT 6144
#define DM 768
#define TOK 128

#define TD 256            // decode d-tile width
#define NTD 3             // d-tiles
#define FC 384            // decode f-chunk
#define NFC 16            // f-chunks
#define NSTEP (FC / 32)   // 12 k-steps per decode block

#define EFT 48            // encode f-tile (3 waves x 16)
#define EBK 128           // encode k-step (f32 cols per staged tile)

using bf16x8 = __attribute__((ext_vector_type(8))) short;
using f32x4  = __attribute__((ext_vector_type(4))) float;

typedef unsigned int u32;
typedef __attribute__((address_space(1))) const u32 gu32;
typedef __attribute__((address_space(3))) u32 lu32;

// async global->LDS, 16B per lane; LDS dest = wave-uniform base + lane*16
__device__ __forceinline__ void stage16(const float* g, float* l) {
  __builtin_amdgcn_global_load_lds((gu32*)g, (lu32*)l, 16, 0, 0);
}

// round-to-nearest-even f32 -> bf16 (branchless; inputs are finite)
__device__ __forceinline__ short f2bf(float f) {
  union { float f; unsigned u; } c; c.f = f;
  unsigned u = c.u;
  u += 0x7fffu + ((u >> 16) & 1u);
  return (short)(u >> 16);
}

// out[j][n][d] = b_dec[j][d]  AND  xb = bf16(x)
__global__ void initcvt_k(const float* __restrict__ b_dec,
                          const float* __restrict__ x,
                          float* __restrict__ out, ushort* __restrict__ xb) {
  int idx = blockIdx.x * 256 + threadIdx.x;
  if (idx < NL * TOK * DM) {
    out[idx] = b_dec[(idx / (TOK * DM)) * DM + (idx % DM)];
    xb[idx] = (ushort)f2bf(x[idx]);
  }
}

// acts[l][n][f] = relu(x[l] @ W_enc[l]^T + b_enc[l]), bf16 output.
// Decode-geometry staging: per step stage [48 f-rows][128 k-cols] f32 = 24 KB
// via 8 global_load_lds/wave; 16B-chunk XOR swizzle (chunk ^ (row&7)) applied
// on the GLOBAL source (LDS dest linear, rule 21) and on the LDS read.
// grid: 6 layers * 128 f-tiles(48) = 768 blocks = exactly 3/CU; 192 thr.
__global__ __launch_bounds__(192, 2) void encode_k(
    const ushort* __restrict__ xb, const float* __restrict__ W_enc,
    const float* __restrict__ b_enc, ushort* __restrict__ acts)
{
  __shared__ float lw[2][EFT][EBK];   // 2 x 24 KB

  const int l  = blockIdx.x / (DT / EFT);
  const int f0 = (blockIdx.x % (DT / EFT)) * EFT;
  const int w    = threadIdx.x >> 6;        // 0..2
  const int lane = threadIdx.x & 63;
  const int lo = lane & 15, hi = lane >> 4;

  const float*  We = W_enc + ((size_t)l * DT + f0) * DM;
  const ushort* Xb = xb + (size_t)l * TOK * DM;

  const int sub = lane >> 5;   // 0..1 (staging row within pair)
  const int ch  = lane & 31;   // staging 16B chunk

  f32x4 acc[8];
  #pragma unroll
  for (int mi = 0; mi < 8; ++mi) acc[mi] = f32x4{0.f, 0.f, 0.f, 0.f};

  // stage step 0 (swizzled source, linear dest)
  #pragma unroll
  for (int q = 0; q < 8; ++q) {
    const int row = w * 16 + q * 2 + sub;
    const int g   = ch ^ (row & 7);
    stage16(We + (size_t)row * DM + g * 4, &lw[0][w * 16 + q * 2][0]);
  }
  __syncthreads();

  int cur = 0;
  #pragma unroll 1
  for (int st = 0; st < DM / EBK; ++st) {
    if (st + 1 < DM / EBK) {
      #pragma unroll
      for (int q = 0; q < 8; ++q) {
        const int row = w * 16 + q * 2 + sub;
        const int g   = ch ^ (row & 7);
        stage16(We + (size_t)row * DM + (st + 1) * EBK + g * 4,
                &lw[cur ^ 1][w * 16 + q * 2][0]);
      }
    }

    const int rr_ = w * 16 + lo;                 // read row; (rr_&7)==(lo&7)
    #pragma unroll
    for (int ks = 0; ks < 4; ++ks) {
      bf16x8 a[8];
      #pragma unroll
      for (int mi = 0; mi < 8; ++mi)
        a[mi] = *(const bf16x8*)(Xb + (size_t)(mi * 16 + lo) * DM
                                 + st * EBK + ks * 32 + hi * 8);

      const int c0 = ks * 8 + ((hi * 2) ^ (lo & 7));
      const int c1 = ks * 8 + ((hi * 2 + 1) ^ (lo & 7));
      const float4 b0 = *(const float4*)&lw[cur][rr_][c0 * 4];
      const float4 b1 = *(const float4*)&lw[cur][rr_][c1 * 4];
      bf16x8 b;
      b[0] = f2bf(b0.x); b[1] = f2bf(b0.y); b[2] = f2bf(b0.z); b[3] = f2bf(b0.w);
      b[4] = f2bf(b1.x); b[5] = f2bf(b1.y); b[6] = f2bf(b1.z); b[7] = f2bf(b1.w);

      #pragma unroll
      for (int mi = 0; mi < 8; ++mi)
        acc[mi] = __builtin_amdgcn_mfma_f32_16x16x32_bf16(a[mi], b, acc[mi], 0, 0, 0);
    }

    __syncthreads();
    cur ^= 1;
  }

  const int f = f0 + w * 16 + lo;
  const float bias = b_enc[l * DT + f];
  #pragma unroll
  for (int mi = 0; mi < 8; ++mi) {
    #pragma unroll
    for (int rr = 0; rr < 4; ++rr) {
      const int n = mi * 16 + hi * 4 + rr;
      float v = acc[mi][rr] + bias;
      v = v > 0.f ? v : 0.f;
      acts[((size_t)l * TOK + n) * DT + f] = (ushort)f2bf(v);
    }
  }
}

// pair enumeration (i <= j), 21 valid decoder blocks
__device__ const int PI_[21] = {0,0,0,0,0,0, 1,1,1,1,1, 2,2,2,2, 3,3,3, 4,4, 5};
__device__ const int PJ_[21] = {0,1,2,3,4,5, 1,2,3,4,5, 2,3,4,5, 3,4,5, 4,5, 5};

// out[j] += acts[i] @ W_dec[i][j], one (i,j) pair per block (uniform work).
// MEASURED (r4/r6): ~62-66 us for the 396 MB W stream = HBM roofline. Do not touch.
__global__ __launch_bounds__(256, 2) void decode_k(
    const ushort* __restrict__ acts, const float* __restrict__ W_dec,
    float* __restrict__ out)
{
  __shared__ float lw[2][32][TD];   // 64 KB

  const int bid = blockIdx.x;
  const int p  = bid / (NTD * NFC);
  const int rm = bid % (NTD * NFC);
  const int c  = rm / NTD;
  const int t  = rm % NTD;
  const int i = PI_[p], j = PJ_[p];
  const int w = threadIdx.x >> 6;
  const int lane = threadIdx.x & 63;
  const int lo = lane & 15, hi = lane >> 4;
  const int fb = c * FC;

  const float*  Wb = W_dec + ((size_t)(i * NL + j) * DT + fb) * DM + t * TD;
  const ushort* Ab = acts + (size_t)i * TOK * DT + fb;

  f32x4 acc[8][4];
  #pragma unroll
  for (int mi = 0; mi < 8; ++mi)
    #pragma unroll
    for (int ni = 0; ni < 4; ++ni)
      acc[mi][ni] = f32x4{0.f, 0.f, 0.f, 0.f};

  #pragma unroll
  for (int q = 0; q < 8; ++q) {
    const int row = w * 8 + q;
    stage16(Wb + (size_t)row * DM + lane * 4, &lw[0][row][0]);
  }
  __syncthreads();

  int cur = 0;
  #pragma unroll 1
  for (int s = 0; s < NSTEP; ++s) {
    if (s + 1 < NSTEP) {
      const float* Ws = Wb + (size_t)(s + 1) * 32 * DM;
      #pragma unroll
      for (int q = 0; q < 8; ++q) {
        const int row = w * 8 + q;
        stage16(Ws + (size_t)row * DM + lane * 4, &lw[cur ^ 1][row][0]);
      }
    }

    bf16x8 a[8];
    #pragma unroll
    for (int mi = 0; mi < 8; ++mi)
      a[mi] = *(const bf16x8*)(Ab + (size_t)(mi * 16 + lo) * DT + s * 32 + hi * 8);

    bf16x8 b[4];
    #pragma unroll
    for (int ni = 0; ni < 4; ++ni) {
      const int col = w * 64 + ni * 16 + lo;
      #pragma unroll
      for (int e = 0; e < 8; ++e)
        b[ni][e] = f2bf(lw[cur][hi * 8 + e][col]);
    }

    #pragma unroll
    for (int mi = 0; mi < 8; ++mi)
      #pragma unroll
      for (int ni = 0; ni < 4; ++ni)
        acc[mi][ni] = __builtin_amdgcn_mfma_f32_16x16x32_bf16(a[mi], b[ni], acc[mi][ni], 0, 0, 0);

    __syncthreads();
    cur ^= 1;
  }

  float* oj = out + (size_t)j * TOK * DM;
  #pragma unroll
  for (int ni = 0; ni < 4; ++ni) {
    const int d = t * TD + w * 64 + ni * 16 + lo;
    #pragma unroll
    for (int mi = 0; mi < 8; ++mi)
      #pragma unroll
      for (int rr = 0; rr < 4; ++rr)
        atomicAdd(oj + (size_t)(mi * 16 + hi * 4 + rr) * DM + d, acc[mi][ni][rr]);
  }
}

extern "C" void kernel_launch(void* const* d_in, const int* in_sizes, int n_in,
                              void* d_out, int out_size, void* d_ws, size_t ws_size,
                              hipStream_t stream) {
  const float* x     = (const float*)d_in[0];
  const float* W_enc = (const float*)d_in[1];
  const float* b_enc = (const float*)d_in[2];
  const float* b_dec = (const float*)d_in[3];
  const float* W_dec = (const float*)d_in[4];
  float* out = (float*)d_out;
  ushort* acts = (ushort*)d_ws;                      // 6*128*6144 bf16 = 9.44 MB
  ushort* xb   = acts + (size_t)NL * TOK * DT;       // 6*128*768 bf16 = 1.18 MB

  initcvt_k<<<dim3((NL * TOK * DM + 255) / 256), dim3(256), 0, stream>>>(b_dec, x, out, xb);
  encode_k<<<dim3(NL * (DT / EFT)), dim3(192), 0, stream>>>(xb, W_enc, b_enc, acts);
  decode_k<<<dim3(21 * NFC * NTD), dim3(256), 0, stream>>>(acts, W_dec, out);
}